// Round 13
// baseline (305.741 us; speedup 1.0000x reference)
//
#include <hip/hip_runtime.h>

#define BB 16
#define NN 1536
#define FF 128
#define SLOPE 0.2f
#define NS 2048
#define CHS 64
#define NCH 24          // NN/CHS
#define TI 16
#define NPB (NN/8)      // 192 k_pardec blocks per sample

// ---- fused: compaction (layer1 only) + bitonic sort of sj + scalar scans ----
__global__ __launch_bounds__(1024) void k_sortpre(
    const int* __restrict__ data,            // non-null => layer 1
    const float* __restrict__ embed, const float* __restrict__ decW,
    const float* __restrict__ aS, const float* __restrict__ aD,
    const float* __restrict__ SJb, long sStride,
    int* __restrict__ actG, int* __restrict__ cntG,
    float* __restrict__ hN, float* __restrict__ sN,
    float* __restrict__ keyG, int* __restrict__ pjG,
    float* __restrict__ SBG, float* __restrict__ SDG)
{
  int b = blockIdx.x, t = threadIdx.x;
  if (b == BB){
    __shared__ float rs[2][2];
    if (t < FF){
      float acc = 0.f;
      for (int k=0;k<FF;++k) acc += embed[(long)NN*FF + k] * decW[k*FF + t];
      hN[t] = acc;
      float ps = acc * aS[t];
      float pd = acc * aD[t];
      #pragma unroll
      for (int o=32;o;o>>=1){ ps += __shfl_down(ps,o); pd += __shfl_down(pd,o); }
      if ((t&63)==0){ rs[0][t>>6]=ps; rs[1][t>>6]=pd; }
    }
    __syncthreads();
    if (t==0){ sN[0]=rs[0][0]+rs[0][1]; sN[1]=rs[1][0]+rs[1][1]; }
    return;
  }

  __shared__ float key[NS]; __shared__ int pj[NS];
  __shared__ float sb[NS]; __shared__ float sd[NS];
  __shared__ int cntS;
  int cnt;
  if (data != nullptr){
    __shared__ int s[256];
    const int PER = NN/256;                  // 6
    int local[NN/256]; int nl = 0;
    if (t < 256){
      int base = t*PER;
      #pragma unroll
      for (int u=0; u<PER; ++u){
        if (data[b*NN + base + u] != 0) local[nl++] = base+u;
      }
      s[t]=nl;
    }
    __syncthreads();
    if (t==0){ int run=0; for (int i=0;i<256;i++){ int v=s[i]; s[i]=run; run+=v; }
               cntG[b]=run; cntS=run; }
    __syncthreads();
    if (t < 256){
      int o = s[t];
      for (int u=0; u<nl; ++u) actG[b*NN + o + u] = local[u];
    }
    __syncthreads();
    cnt = cntS;
  } else {
    cnt = cntG[b];
  }

  const float* SJ = SJb + (long)b*sStride;
  const int* act = (data != nullptr) ? actG + b*NN : nullptr;
  int NSort = 32; while (NSort < cnt) NSort <<= 1;    // <= 2048

  for (int e=t; e<NSort; e+=1024){
    if (e<cnt){ int io = act ? act[e] : e; key[e]=SJ[io]; pj[e]=io; }
    else { key[e]=__builtin_inff(); pj[e]=0; }
  }
  __syncthreads();
  for (int k=2; k<=NSort; k<<=1){
    for (int j=k>>1; j>0; j>>=1){
      for (int e=t; e<NSort; e+=1024){
        int l = e ^ j;
        if (l > e){
          bool asc = ((e & k) == 0);
          float a0=key[e], a1=key[l];
          if (asc ? (a0>a1) : (a0<a1)){
            key[e]=a1; key[l]=a0; int p=pj[e]; pj[e]=pj[l]; pj[l]=p;
          }
        }
      }
      __syncthreads();
    }
  }
  for (int e=t; e<NSort; e+=1024){
    if (e<cnt){ float kk=key[e]; sb[e]=__expf(kk); sd[e]=__expf(SLOPE*kk); }
    else { sb[e]=0.f; sd[e]=0.f; }
  }
  __syncthreads();
  for (int off=1; off<NSort; off<<=1){
    float t0[2], t1[2]; int ne=0;
    for (int e=t; e<NSort; e+=1024){
      t0[ne] = (e>=off) ? sb[e-off] : 0.f;
      t1[ne] = (e>=off) ? sd[e-off] : 0.f;
      ne++;
    }
    __syncthreads();
    ne=0;
    for (int e=t; e<NSort; e+=1024){ sb[e]+=t0[ne]; sd[e]+=t1[ne]; ne++; }
    __syncthreads();
  }
  for (int e=t; e<cnt; e+=1024){
    keyG[(long)b*NN+e]=key[e]; pjG[(long)b*NN+e]=pj[e];
    SBG[(long)b*NN+e]=sb[e];   SDG[(long)b*NN+e]=sd[e];
  }
}

// ---- row-matmul (layer 1 only): H = X @ W, SI = H@aSrc, SJ = H@aDst ----
__global__ __launch_bounds__(128) void k_rowmm(const float* __restrict__ Xv,
    const float* __restrict__ W, const float* __restrict__ aS, const float* __restrict__ aD,
    float* __restrict__ H, float* __restrict__ SI, float* __restrict__ SJ)
{
  int r0 = blockIdx.x*8;
  int f = threadIdx.x;
  __shared__ float xs[8][FF];
  #pragma unroll
  for (int r=0;r<8;++r) xs[r][f] = Xv[(long)(r0+r)*FF + f];
  __syncthreads();
  float acc[8]={0.f,0.f,0.f,0.f,0.f,0.f,0.f,0.f};
  for (int k=0;k<FF;++k){
    float w = W[k*FF + f];
    #pragma unroll
    for (int r=0;r<8;++r) acc[r] += xs[r][k]*w;
  }
  float as = aS[f], ad = aD[f];
  __shared__ float red[2][8][2];
  #pragma unroll
  for (int r=0;r<8;++r){
    H[(long)(r0+r)*FF + f] = acc[r];
    float ps = acc[r]*as, pd = acc[r]*ad;
    #pragma unroll
    for (int o=32;o;o>>=1){ ps += __shfl_down(ps,o); pd += __shfl_down(pd,o); }
    if ((f&63)==0){ red[0][r][f>>6]=ps; red[1][r][f>>6]=pd; }
  }
  __syncthreads();
  if (f<8){
    SI[r0+f]=red[0][f][0]+red[0][f][1]; SJ[r0+f]=red[1][f][0]+red[1][f][1];
  }
}

// ---- agg stage 2: within-chunk vector prefixes, 8-deep prefetch pipeline ----
__global__ __launch_bounds__(128) void k_chunk(
    const float* __restrict__ keyG, const int* __restrict__ pjG,
    const int* __restrict__ cntArr,
    const float* __restrict__ Hb, long hStride,
    float* __restrict__ PP, float* __restrict__ PM)
{
  int b = blockIdx.y, c = blockIdx.x, f = threadIdx.x;
  int cnt = cntArr[b];
  int k0 = c*CHS;
  if (k0 >= cnt) return;
  int k1 = k0+CHS; if (k1 > cnt) k1 = cnt;
  int kn = k1-k0;
  const float* H = Hb + (long)b*hStride + f;
  __shared__ int pjs[CHS]; __shared__ float wbs[CHS], wds[CHS];
  if (f < CHS && f < kn){
    float kk = keyG[(long)b*NN + k0 + f];
    pjs[f] = pjG[(long)b*NN + k0 + f];
    wbs[f] = __expf(kk);
    wds[f] = __expf(SLOPE*kk);
  }
  __syncthreads();
  float accB=0.f, accD=0.f;
  float hbuf[8];
  #pragma unroll
  for (int i=0;i<8;i++) hbuf[i] = (i<kn) ? H[(long)pjs[i]*FF] : 0.f;
  long obase = ((long)b*NN + k0)*FF + f;
  int k=0;
  for (; k+8<=kn; k+=8){
    #pragma unroll
    for (int u=0;u<8;u++){
      float hv = hbuf[u];
      int kp = k+u+8;
      hbuf[u] = (kp<kn) ? H[(long)pjs[kp]*FF] : 0.f;
      accB = fmaf(wbs[k+u], hv, accB);
      accD = fmaf(wds[k+u], hv, accD);
      PP[obase + (long)(k+u)*FF] = accB;
      PM[obase + (long)(k+u)*FF] = accD;
    }
  }
  for (; k<kn; ++k){
    float hv = H[(long)pjs[k]*FF];
    accB = fmaf(wbs[k], hv, accB);
    accD = fmaf(wds[k], hv, accD);
    PP[obase + (long)k*FF] = accB;
    PM[obase + (long)k*FF] = accD;
  }
}

// ---- layer-1 aggout FUSED with layer-2 projection: writes H2/SI2/SJ2 ----
__global__ __launch_bounds__(128) void k_aggout_mm(
    const float* __restrict__ keyG, const float* __restrict__ SBG, const float* __restrict__ SDG,
    const float* __restrict__ PP, const float* __restrict__ PM,
    const float* __restrict__ SI1, const int* __restrict__ actB,
    const int* __restrict__ cntArr,
    const float* __restrict__ W, const float* __restrict__ aS, const float* __restrict__ aD,
    float* __restrict__ Hout, float* __restrict__ SIo, float* __restrict__ SJo)
{
  int b = blockIdx.y;
  int cnt = cntArr[b];
  int r0 = blockIdx.x*TI;
  if (r0 >= cnt) return;
  int f = threadIdx.x;
  const int* act = actB + b*NN;
  __shared__ float keys[NN];
  __shared__ float offB[NCH][FF], offD[NCH][FF];
  __shared__ int kk[TI]; __shared__ float sis[TI];
  __shared__ float xs2[TI][FF];

  for (int e=f; e<cnt; e+=128) keys[e] = keyG[(long)b*NN + e];
  int nch = (cnt + CHS - 1)/CHS;
  for (int c=0; c<nch; ++c){
    int kend = (c+1)*CHS; if (kend > cnt) kend = cnt; kend -= 1;
    offB[c][f] = PP[((long)b*NN+kend)*FF+f];
    offD[c][f] = PM[((long)b*NN+kend)*FF+f];
  }
  float rb=0.f, rd=0.f;
  for (int c=0; c<nch; ++c){
    float tb=offB[c][f], td=offD[c][f];
    offB[c][f]=rb; offD[c][f]=rd;
    rb+=tb; rd+=td;
  }
  float TB = rb;
  __syncthreads();
  if (f < TI){
    int r = r0 + f;
    float si=0.f; int k=0;
    if (r < cnt){
      si = SI1[act[r]];
      float th = -si;
      int lo=0, hi=cnt;
      while (lo<hi){ int mid=(lo+hi)>>1; if (keys[mid]<=th) lo=mid+1; else hi=mid; }
      k = lo;
    }
    kk[f]=k; sis[f]=si;
  }
  __syncthreads();
  float TBs = SBG[(long)b*NN + (cnt-1)];
  int rmax = cnt - r0; if (rmax > TI) rmax = TI;
  for (int r=0; r<TI; ++r){
    float v = 0.f;
    if (r < rmax){
      int k = kk[r]; float si = sis[r];
      float PB=0.f, PD=0.f, SBv=0.f, SDv=0.f;
      if (k > 0){
        int c = (k-1)/CHS;
        PB = PP[((long)b*NN+(k-1))*FF+f] + offB[c][f];
        PD = PM[((long)b*NN+(k-1))*FF+f] + offD[c][f];
        SBv = SBG[(long)b*NN+(k-1)];
        SDv = SDG[(long)b*NN+(k-1)];
      }
      float ai=__expf(si), ci=__expf(SLOPE*si);
      float num = ai*(TB -PB ) + ci*PD;
      float den = ai*(TBs-SBv) + ci*SDv;
      float o2 = num/den;
      v = (o2>0.f)? o2 : (__expf(o2)-1.f);
    }
    xs2[r][f] = v;
  }
  __syncthreads();
  // layer-2 projection of the 16 rows
  float acc2[TI];
  #pragma unroll
  for (int u=0;u<TI;++u) acc2[u]=0.f;
  for (int k=0;k<FF;++k){
    float w = W[k*FF + f];
    #pragma unroll
    for (int u=0;u<TI;++u) acc2[u] += xs2[u][k]*w;
  }
  float as = aS[f], ad = aD[f];
  __shared__ float red[2][TI][2];
  #pragma unroll
  for (int u=0;u<TI;++u){
    int rr=r0+u;
    if (rr<cnt) Hout[((long)b*NN+rr)*FF+f] = acc2[u];
    float ps = acc2[u]*as, pd = acc2[u]*ad;
    #pragma unroll
    for (int o=32;o;o>>=1){ ps += __shfl_down(ps,o); pd += __shfl_down(pd,o); }
    if ((f&63)==0){ red[0][u][f>>6]=ps; red[1][u][f>>6]=pd; }
  }
  __syncthreads();
  if (f < TI){
    int rr=r0+f;
    if (rr<cnt){
      SIo[(long)b*NN+rr]=red[0][f][0]+red[0][f][1];
      SJo[(long)b*NN+rr]=red[1][f][0]+red[1][f][1];
    }
  }
}

// ---- layer-2 aggout (plain): writes elu(out) to XC ----
__global__ __launch_bounds__(128) void k_aggout(
    const float* __restrict__ keyG, const float* __restrict__ SBG, const float* __restrict__ SDG,
    const float* __restrict__ PP, const float* __restrict__ PM,
    const float* __restrict__ SIb,
    const int* __restrict__ cntArr, float* __restrict__ XoB)
{
  int b = blockIdx.y;
  int cnt = cntArr[b];
  int r0 = blockIdx.x*TI;
  if (r0 >= cnt) return;
  int f = threadIdx.x;
  const float* SI = SIb + (long)b*NN;
  float* xo = XoB + (long)b*NN*FF;
  __shared__ float keys[NN];
  __shared__ float offB[NCH][FF], offD[NCH][FF];
  __shared__ int kk[TI]; __shared__ float sis[TI];

  for (int e=f; e<cnt; e+=128) keys[e] = keyG[(long)b*NN + e];
  int nch = (cnt + CHS - 1)/CHS;
  for (int c=0; c<nch; ++c){
    int kend = (c+1)*CHS; if (kend > cnt) kend = cnt; kend -= 1;
    offB[c][f] = PP[((long)b*NN+kend)*FF+f];
    offD[c][f] = PM[((long)b*NN+kend)*FF+f];
  }
  float rb=0.f, rd=0.f;
  for (int c=0; c<nch; ++c){
    float tb=offB[c][f], td=offD[c][f];
    offB[c][f]=rb; offD[c][f]=rd;
    rb+=tb; rd+=td;
  }
  float TB = rb;
  __syncthreads();
  if (f < TI){
    int r = r0 + f;
    float si=0.f; int k=0;
    if (r < cnt){
      si = SI[r];
      float th = -si;
      int lo=0, hi=cnt;
      while (lo<hi){ int mid=(lo+hi)>>1; if (keys[mid]<=th) lo=mid+1; else hi=mid; }
      k = lo;
    }
    kk[f]=k; sis[f]=si;
  }
  __syncthreads();
  float TBs = SBG[(long)b*NN + (cnt-1)];
  int rmax = cnt - r0; if (rmax > TI) rmax = TI;
  for (int r=0; r<rmax; ++r){
    int k = kk[r]; float si = sis[r];
    float PB=0.f, PD=0.f, SBv=0.f, SDv=0.f;
    if (k > 0){
      int c = (k-1)/CHS;
      PB = PP[((long)b*NN+(k-1))*FF+f] + offB[c][f];
      PD = PM[((long)b*NN+(k-1))*FF+f] + offD[c][f];
      SBv = SBG[(long)b*NN+(k-1)];
      SDv = SDG[(long)b*NN+(k-1)];
    }
    float ai=__expf(si), ci=__expf(SLOPE*si);
    float num = ai*(TB -PB ) + ci*PD;
    float den = ai*(TBs-SBv) + ci*SDv;
    float o2 = num/den;
    xo[(long)(r0+r)*FF + f] = (o2>0.f)? o2 : (__expf(o2)-1.f);
  }
}

// ---- FUSED param head + kld partial + decoder projection (mean in LDS) ----
__global__ __launch_bounds__(256) void k_pardec(const float* __restrict__ XC,
    const float* __restrict__ pW, const float* __restrict__ pB,
    const float* __restrict__ decW, const float* __restrict__ dAd,
    float* __restrict__ KPART, float* __restrict__ H3, float* __restrict__ SJd,
    const int* __restrict__ cntArr)
{
  int b = blockIdx.y; int cnt = cntArr[b];
  int bx = blockIdx.x;
  int r0 = bx*8;
  int t = threadIdx.x;
  if (r0>=cnt){
    if (t==0) KPART[b*NPB + bx] = 0.f;
    return;
  }
  const float* X = XC + (long)b*NN*FF;
  __shared__ float xs[8][FF];
  for (int e=t; e<8*FF; e+=256){
    int r=e>>7, k=e&127; int rr=r0+r;
    xs[r][k] = (rr<cnt) ? X[(long)rr*FF+k] : 0.f;
  }
  __syncthreads();
  float acc[8]={0.f,0.f,0.f,0.f,0.f,0.f,0.f,0.f};
  for (int k=0;k<FF;++k){
    float w = pW[k*2*FF + t];
    #pragma unroll
    for (int r=0;r<8;++r) acc[r]+=xs[r][k]*w;
  }
  float bb = pB[t];
  float kacc=0.f;
  #pragma unroll
  for (int r=0;r<8;++r){
    int rr=r0+r;
    if (rr>=cnt) continue;
    float v = acc[r]+bb;
    if (t<FF) kacc += v*v;
    else kacc += __expf(v)-v-1.f;
  }
  #pragma unroll
  for (int o=32;o;o>>=1) kacc += __shfl_down(kacc,o);
  __shared__ float rw[4];
  if ((t&63)==0) rw[t>>6]=kacc;
  __syncthreads();
  if (t==0) KPART[b*NPB + bx] = rw[0]+rw[1]+rw[2]+rw[3];
  // mean rows into LDS
  __shared__ float ms[8][FF];
  if (t < FF){
    #pragma unroll
    for (int r=0;r<8;++r){
      int rr=r0+r;
      ms[r][t] = (rr<cnt) ? acc[r]+bb : 0.f;
    }
  }
  __syncthreads();
  // decoder projection: half h handles rows h*4..h*4+3
  int h = t>>7, f = t&127;
  float a2[4]={0.f,0.f,0.f,0.f};
  for (int k=0;k<FF;++k){
    float w = decW[k*FF + f];
    #pragma unroll
    for (int u=0;u<4;++u) a2[u] += ms[h*4+u][k]*w;
  }
  float ad = dAd[f];
  __shared__ float redD[8][2];
  #pragma unroll
  for (int u=0;u<4;++u){
    int rq = h*4+u; int rr = r0+rq;
    if (rr<cnt) H3[((long)b*NN+rr)*FF+f] = a2[u];
    float pd = a2[u]*ad;
    #pragma unroll
    for (int o=32;o;o>>=1) pd += __shfl_down(pd,o);
    if ((t&63)==0) redD[rq][(t>>6)&1]=pd;
  }
  __syncthreads();
  if (t<8){
    int rr=r0+t;
    if (rr<cnt) SJd[(long)b*NN+rr]=redD[t][0]+redD[t][1];
  }
}

// ---- head: blocks 0..15 = decoder reduction + MLP; block 16 = kld ----
__global__ __launch_bounds__(128) void k_head(const float* __restrict__ H3,
    const float* __restrict__ SJd,
    const float* __restrict__ hN, const float* __restrict__ sN,
    const float* __restrict__ KPART, const int* __restrict__ cntArr,
    const float* __restrict__ W1, const float* __restrict__ b1,
    const float* __restrict__ W2, const float* __restrict__ b2,
    float* __restrict__ out)
{
  int b = blockIdx.x;
  int f = threadIdx.x;
  __shared__ float rw[2];
  if (b < BB){
    int cnt_b = cntArr[b];
    float siN=sN[0], sjN=sN[1];
    const float* H = H3 + (long)b*NN*FF;
    const float* SJ = SJd + (long)b*NN;
    float num=0.f, den=0.f;
    __shared__ float sjs[128];
    for (int r0=0; r0<cnt_b; r0+=128){
      int rn = cnt_b - r0; if (rn>128) rn=128;
      __syncthreads();
      if (f<rn) sjs[f]=SJ[r0+f];
      __syncthreads();
      #pragma unroll 4
      for (int r=0;r<rn;++r){
        float x=siN+sjs[r];
        float e=(x>=0.f)? x : SLOPE*x;
        float w=__expf(e);
        num += w*H[(long)(r0+r)*FF+f];
        den += w;
      }
    }
    float xN=siN+sjN; float eN=(xN>=0.f)?xN:SLOPE*xN; float wN=__expf(eN);
    num += wN*hN[f]; den += wN;
    float v = num/den;
    __shared__ float feats[FF];
    feats[f] = (v>0.f)? v : 0.f;
    __syncthreads();
    float acc=0.f;
    for (int k=0;k<FF;++k) acc += feats[k]*W1[k*FF+f];
    acc += b1[f];
    acc = (acc>0.f)? acc : 0.f;
    float p = acc*W2[f];
    #pragma unroll
    for (int o=32;o;o>>=1) p += __shfl_down(p,o);
    if ((f&63)==0) rw[f>>6]=p;
    __syncthreads();
    if (f==0) out[b] = rw[0]+rw[1]+b2[0];
  } else {
    float s=0.f;
    for (int bb=0;bb<BB;++bb){
      float part=0.f;
      for (int c=f;c<NPB;c+=128) part += KPART[bb*NPB + c];
      #pragma unroll
      for (int o=32;o;o>>=1) part += __shfl_down(part,o);
      if ((f&63)==0) rw[f>>6]=part;
      __syncthreads();
      float tot = rw[0]+rw[1];
      int c=cntArr[bb]; float cf = (c>0)? (float)c : 1.f;
      s += 0.5f*tot/cf;
      __syncthreads();
    }
    if (f==0) out[16]=s;
  }
}

extern "C" void kernel_launch(void* const* d_in, const int* in_sizes, int n_in,
                              void* d_out, int out_size, void* d_ws, size_t ws_size,
                              hipStream_t stream)
{
  const int*   data  = (const int*)d_in[0];
  const float* embed = (const float*)d_in[1];
  const float* encW  = (const float*)d_in[2];
  const float* encAs = (const float*)d_in[3];
  const float* encAd = (const float*)d_in[4];
  const float* pW    = (const float*)d_in[5];
  const float* pB    = (const float*)d_in[6];
  const float* decW  = (const float*)d_in[7];
  const float* decAs = (const float*)d_in[8];
  const float* decAd = (const float*)d_in[9];
  const float* oW1   = (const float*)d_in[10];
  const float* oB1   = (const float*)d_in[11];
  const float* oW2   = (const float*)d_in[12];
  const float* oB2   = (const float*)d_in[13];
  float* out = (float*)d_out;

  float* w = (float*)d_ws;
  long o = 0;
  float* H1   = w+o; o += (long)NN*FF;
  float* H2   = w+o; o += (long)BB*NN*FF;   // layer-2 proj; reused as H3
  float* XC   = w+o; o += (long)BB*NN*FF;   // layer-2 attention output
  float* PP   = w+o; o += (long)BB*NN*FF;
  float* PM   = w+o; o += (long)BB*NN*FF;
  float* SI1  = w+o; o += NN;
  float* SJ1  = w+o; o += NN;
  float* SI2  = w+o; o += (long)BB*NN;
  float* SJ2  = w+o; o += (long)BB*NN;     // enc layer-2 sj; reused for dec sj
  float* KPART= w+o; o += (long)BB*NPB;
  float* hN   = w+o; o += FF;
  float* sN   = w+o; o += 2;
  float* keyG = w+o; o += (long)BB*NN;
  float* SBG  = w+o; o += (long)BB*NN;
  float* SDG  = w+o; o += (long)BB*NN;
  int* act = (int*)(w+o); o += (long)BB*NN;
  int* pjG = (int*)(w+o); o += (long)BB*NN;
  int* cnt = (int*)(w+o); o += BB;
  (void)in_sizes; (void)n_in; (void)out_size; (void)ws_size;

  // layer 1 projection (sample-shared)
  k_rowmm<<<NN/8,128,0,stream>>>(embed, encW, encAs, encAd, H1, SI1, SJ1);
  // compaction + sort + scalar scans (block 16: h_N/s_N)
  k_sortpre<<<BB+1,1024,0,stream>>>(data, embed, decW, decAs, decAd,
      SJ1, 0L, act, cnt, hN, sN, keyG, pjG, SBG, SDG);
  k_chunk<<<dim3(NCH,BB),128,0,stream>>>(keyG, pjG, cnt, H1, 0L, PP, PM);
  // layer-1 attention + layer-2 projection fused
  k_aggout_mm<<<dim3(NN/TI,BB),128,0,stream>>>(keyG, SBG, SDG, PP, PM,
      SI1, act, cnt, encW + FF*FF, encAs + FF, encAd + FF, H2, SI2, SJ2);
  // layer 2 attention
  k_sortpre<<<BB,1024,0,stream>>>(nullptr, embed, decW, decAs, decAd,
      SJ2, (long)NN, act, cnt, hN, sN, keyG, pjG, SBG, SDG);
  k_chunk<<<dim3(NCH,BB),128,0,stream>>>(keyG, pjG, cnt, H2, (long)NN*FF, PP, PM);
  k_aggout<<<dim3(NN/TI,BB),128,0,stream>>>(keyG, SBG, SDG, PP, PM,
      SI2, cnt, XC);
  // param head + kld + decoder projection fused (H3 into H2 buffer, dec sj into SJ2)
  k_pardec<<<dim3(NPB,BB),256,0,stream>>>(XC, pW, pB, decW, decAd,
      KPART, H2 /*H3*/, SJ2 /*dec sj*/, cnt);
  // decoder reduction + MLP head + kld sum
  k_head<<<BB+1,128,0,stream>>>(H2 /*H3*/, SJ2, hN, sN, KPART, cnt,
      oW1, oB1, oW2, oB2, out);
}

// Round 14
// 277.559 us; speedup vs baseline: 1.1015x; 1.1015x over previous
//
#include <hip/hip_runtime.h>

#define BB 16
#define NN 1536
#define FF 128
#define SLOPE 0.2f
#define NS 2048
#define CHS 64
#define NCH 24          // NN/CHS
#define TI 16
#define NPB (NN/8)      // 192 k_pardec blocks per sample
#define NDC 24          // decoder reduction chunks (64 rows each)

// ---- fused: compaction (layer1 only) + bitonic sort of sj + scalar scans ----
__global__ __launch_bounds__(1024) void k_sortpre(
    const int* __restrict__ data,            // non-null => layer 1
    const float* __restrict__ embed, const float* __restrict__ decW,
    const float* __restrict__ aS, const float* __restrict__ aD,
    const float* __restrict__ SJb, long sStride,
    int* __restrict__ actG, int* __restrict__ cntG,
    float* __restrict__ hN, float* __restrict__ sN,
    float* __restrict__ keyG, int* __restrict__ pjG,
    float* __restrict__ SBG, float* __restrict__ SDG)
{
  int b = blockIdx.x, t = threadIdx.x;
  if (b == BB){
    __shared__ float rs[2][2];
    if (t < FF){
      float acc = 0.f;
      for (int k=0;k<FF;++k) acc += embed[(long)NN*FF + k] * decW[k*FF + t];
      hN[t] = acc;
      float ps = acc * aS[t];
      float pd = acc * aD[t];
      #pragma unroll
      for (int o=32;o;o>>=1){ ps += __shfl_down(ps,o); pd += __shfl_down(pd,o); }
      if ((t&63)==0){ rs[0][t>>6]=ps; rs[1][t>>6]=pd; }
    }
    __syncthreads();
    if (t==0){ sN[0]=rs[0][0]+rs[0][1]; sN[1]=rs[1][0]+rs[1][1]; }
    return;
  }

  __shared__ float key[NS]; __shared__ int pj[NS];
  __shared__ float sb[NS]; __shared__ float sd[NS];
  __shared__ int cntS;
  int cnt;
  if (data != nullptr){
    __shared__ int s[256];
    const int PER = NN/256;                  // 6
    int local[NN/256]; int nl = 0;
    if (t < 256){
      int base = t*PER;
      #pragma unroll
      for (int u=0; u<PER; ++u){
        if (data[b*NN + base + u] != 0) local[nl++] = base+u;
      }
      s[t]=nl;
    }
    __syncthreads();
    if (t==0){ int run=0; for (int i=0;i<256;i++){ int v=s[i]; s[i]=run; run+=v; }
               cntG[b]=run; cntS=run; }
    __syncthreads();
    if (t < 256){
      int o = s[t];
      for (int u=0; u<nl; ++u) actG[b*NN + o + u] = local[u];
    }
    __syncthreads();
    cnt = cntS;
  } else {
    cnt = cntG[b];
  }

  const float* SJ = SJb + (long)b*sStride;
  const int* act = (data != nullptr) ? actG + b*NN : nullptr;
  int NSort = 32; while (NSort < cnt) NSort <<= 1;    // <= 2048

  for (int e=t; e<NSort; e+=1024){
    if (e<cnt){ int io = act ? act[e] : e; key[e]=SJ[io]; pj[e]=io; }
    else { key[e]=__builtin_inff(); pj[e]=0; }
  }
  __syncthreads();
  for (int k=2; k<=NSort; k<<=1){
    for (int j=k>>1; j>0; j>>=1){
      for (int e=t; e<NSort; e+=1024){
        int l = e ^ j;
        if (l > e){
          bool asc = ((e & k) == 0);
          float a0=key[e], a1=key[l];
          if (asc ? (a0>a1) : (a0<a1)){
            key[e]=a1; key[l]=a0; int p=pj[e]; pj[e]=pj[l]; pj[l]=p;
          }
        }
      }
      __syncthreads();
    }
  }
  for (int e=t; e<NSort; e+=1024){
    if (e<cnt){ float kk=key[e]; sb[e]=__expf(kk); sd[e]=__expf(SLOPE*kk); }
    else { sb[e]=0.f; sd[e]=0.f; }
  }
  __syncthreads();
  for (int off=1; off<NSort; off<<=1){
    float t0[2], t1[2]; int ne=0;
    for (int e=t; e<NSort; e+=1024){
      t0[ne] = (e>=off) ? sb[e-off] : 0.f;
      t1[ne] = (e>=off) ? sd[e-off] : 0.f;
      ne++;
    }
    __syncthreads();
    ne=0;
    for (int e=t; e<NSort; e+=1024){ sb[e]+=t0[ne]; sd[e]+=t1[ne]; ne++; }
    __syncthreads();
  }
  for (int e=t; e<cnt; e+=1024){
    keyG[(long)b*NN+e]=key[e]; pjG[(long)b*NN+e]=pj[e];
    SBG[(long)b*NN+e]=sb[e];   SDG[(long)b*NN+e]=sd[e];
  }
}

// ---- row-matmul (layer 1 only): H = X @ W, SI = H@aSrc, SJ = H@aDst ----
__global__ __launch_bounds__(128) void k_rowmm(const float* __restrict__ Xv,
    const float* __restrict__ W, const float* __restrict__ aS, const float* __restrict__ aD,
    float* __restrict__ H, float* __restrict__ SI, float* __restrict__ SJ)
{
  int r0 = blockIdx.x*8;
  int f = threadIdx.x;
  __shared__ float xs[8][FF];
  #pragma unroll
  for (int r=0;r<8;++r) xs[r][f] = Xv[(long)(r0+r)*FF + f];
  __syncthreads();
  float acc[8]={0.f,0.f,0.f,0.f,0.f,0.f,0.f,0.f};
  for (int k=0;k<FF;++k){
    float w = W[k*FF + f];
    #pragma unroll
    for (int r=0;r<8;++r) acc[r] += xs[r][k]*w;
  }
  float as = aS[f], ad = aD[f];
  __shared__ float red[2][8][2];
  #pragma unroll
  for (int r=0;r<8;++r){
    H[(long)(r0+r)*FF + f] = acc[r];
    float ps = acc[r]*as, pd = acc[r]*ad;
    #pragma unroll
    for (int o=32;o;o>>=1){ ps += __shfl_down(ps,o); pd += __shfl_down(pd,o); }
    if ((f&63)==0){ red[0][r][f>>6]=ps; red[1][r][f>>6]=pd; }
  }
  __syncthreads();
  if (f<8){
    SI[r0+f]=red[0][f][0]+red[0][f][1]; SJ[r0+f]=red[1][f][0]+red[1][f][1];
  }
}

// ---- agg stage 2: within-chunk vector prefixes, 8-deep prefetch pipeline ----
__global__ __launch_bounds__(128) void k_chunk(
    const float* __restrict__ keyG, const int* __restrict__ pjG,
    const int* __restrict__ cntArr,
    const float* __restrict__ Hb, long hStride,
    float* __restrict__ PP, float* __restrict__ PM)
{
  int b = blockIdx.y, c = blockIdx.x, f = threadIdx.x;
  int cnt = cntArr[b];
  int k0 = c*CHS;
  if (k0 >= cnt) return;
  int k1 = k0+CHS; if (k1 > cnt) k1 = cnt;
  int kn = k1-k0;
  const float* H = Hb + (long)b*hStride + f;
  __shared__ int pjs[CHS]; __shared__ float wbs[CHS], wds[CHS];
  if (f < CHS && f < kn){
    float kk = keyG[(long)b*NN + k0 + f];
    pjs[f] = pjG[(long)b*NN + k0 + f];
    wbs[f] = __expf(kk);
    wds[f] = __expf(SLOPE*kk);
  }
  __syncthreads();
  float accB=0.f, accD=0.f;
  float hbuf[8];
  #pragma unroll
  for (int i=0;i<8;i++) hbuf[i] = (i<kn) ? H[(long)pjs[i]*FF] : 0.f;
  long obase = ((long)b*NN + k0)*FF + f;
  int k=0;
  for (; k+8<=kn; k+=8){
    #pragma unroll
    for (int u=0;u<8;u++){
      float hv = hbuf[u];
      int kp = k+u+8;
      hbuf[u] = (kp<kn) ? H[(long)pjs[kp]*FF] : 0.f;
      accB = fmaf(wbs[k+u], hv, accB);
      accD = fmaf(wds[k+u], hv, accD);
      PP[obase + (long)(k+u)*FF] = accB;
      PM[obase + (long)(k+u)*FF] = accD;
    }
  }
  for (; k<kn; ++k){
    float hv = H[(long)pjs[k]*FF];
    accB = fmaf(wbs[k], hv, accB);
    accD = fmaf(wds[k], hv, accD);
    PP[obase + (long)k*FF] = accB;
    PM[obase + (long)k*FF] = accD;
  }
}

// ---- layer-1 aggout FUSED with layer-2 projection: writes H2/SI2/SJ2 ----
__global__ __launch_bounds__(128) void k_aggout_mm(
    const float* __restrict__ keyG, const float* __restrict__ SBG, const float* __restrict__ SDG,
    const float* __restrict__ PP, const float* __restrict__ PM,
    const float* __restrict__ SI1, const int* __restrict__ actB,
    const int* __restrict__ cntArr,
    const float* __restrict__ W, const float* __restrict__ aS, const float* __restrict__ aD,
    float* __restrict__ Hout, float* __restrict__ SIo, float* __restrict__ SJo)
{
  int b = blockIdx.y;
  int cnt = cntArr[b];
  int r0 = blockIdx.x*TI;
  if (r0 >= cnt) return;
  int f = threadIdx.x;
  const int* act = actB + b*NN;
  __shared__ float keys[NN];
  __shared__ float offB[NCH][FF], offD[NCH][FF];
  __shared__ int kk[TI]; __shared__ float sis[TI];
  __shared__ float xs2[TI][FF];

  for (int e=f; e<cnt; e+=128) keys[e] = keyG[(long)b*NN + e];
  int nch = (cnt + CHS - 1)/CHS;
  for (int c=0; c<nch; ++c){
    int kend = (c+1)*CHS; if (kend > cnt) kend = cnt; kend -= 1;
    offB[c][f] = PP[((long)b*NN+kend)*FF+f];
    offD[c][f] = PM[((long)b*NN+kend)*FF+f];
  }
  float rb=0.f, rd=0.f;
  for (int c=0; c<nch; ++c){
    float tb=offB[c][f], td=offD[c][f];
    offB[c][f]=rb; offD[c][f]=rd;
    rb+=tb; rd+=td;
  }
  float TB = rb;
  __syncthreads();
  if (f < TI){
    int r = r0 + f;
    float si=0.f; int k=0;
    if (r < cnt){
      si = SI1[act[r]];
      float th = -si;
      int lo=0, hi=cnt;
      while (lo<hi){ int mid=(lo+hi)>>1; if (keys[mid]<=th) lo=mid+1; else hi=mid; }
      k = lo;
    }
    kk[f]=k; sis[f]=si;
  }
  __syncthreads();
  float TBs = SBG[(long)b*NN + (cnt-1)];
  int rmax = cnt - r0; if (rmax > TI) rmax = TI;
  for (int r=0; r<TI; ++r){
    float v = 0.f;
    if (r < rmax){
      int k = kk[r]; float si = sis[r];
      float PB=0.f, PD=0.f, SBv=0.f, SDv=0.f;
      if (k > 0){
        int c = (k-1)/CHS;
        PB = PP[((long)b*NN+(k-1))*FF+f] + offB[c][f];
        PD = PM[((long)b*NN+(k-1))*FF+f] + offD[c][f];
        SBv = SBG[(long)b*NN+(k-1)];
        SDv = SDG[(long)b*NN+(k-1)];
      }
      float ai=__expf(si), ci=__expf(SLOPE*si);
      float num = ai*(TB -PB ) + ci*PD;
      float den = ai*(TBs-SBv) + ci*SDv;
      float o2 = num/den;
      v = (o2>0.f)? o2 : (__expf(o2)-1.f);
    }
    xs2[r][f] = v;
  }
  __syncthreads();
  float acc2[TI];
  #pragma unroll
  for (int u=0;u<TI;++u) acc2[u]=0.f;
  for (int k=0;k<FF;++k){
    float w = W[k*FF + f];
    #pragma unroll
    for (int u=0;u<TI;++u) acc2[u] += xs2[u][k]*w;
  }
  float as = aS[f], ad = aD[f];
  __shared__ float red[2][TI][2];
  #pragma unroll
  for (int u=0;u<TI;++u){
    int rr=r0+u;
    if (rr<cnt) Hout[((long)b*NN+rr)*FF+f] = acc2[u];
    float ps = acc2[u]*as, pd = acc2[u]*ad;
    #pragma unroll
    for (int o=32;o;o>>=1){ ps += __shfl_down(ps,o); pd += __shfl_down(pd,o); }
    if ((f&63)==0){ red[0][u][f>>6]=ps; red[1][u][f>>6]=pd; }
  }
  __syncthreads();
  if (f < TI){
    int rr=r0+f;
    if (rr<cnt){
      SIo[(long)b*NN+rr]=red[0][f][0]+red[0][f][1];
      SJo[(long)b*NN+rr]=red[1][f][0]+red[1][f][1];
    }
  }
}

// ---- layer-2 aggout (plain): writes elu(out) to XC ----
__global__ __launch_bounds__(128) void k_aggout(
    const float* __restrict__ keyG, const float* __restrict__ SBG, const float* __restrict__ SDG,
    const float* __restrict__ PP, const float* __restrict__ PM,
    const float* __restrict__ SIb,
    const int* __restrict__ cntArr, float* __restrict__ XoB)
{
  int b = blockIdx.y;
  int cnt = cntArr[b];
  int r0 = blockIdx.x*TI;
  if (r0 >= cnt) return;
  int f = threadIdx.x;
  const float* SI = SIb + (long)b*NN;
  float* xo = XoB + (long)b*NN*FF;
  __shared__ float keys[NN];
  __shared__ float offB[NCH][FF], offD[NCH][FF];
  __shared__ int kk[TI]; __shared__ float sis[TI];

  for (int e=f; e<cnt; e+=128) keys[e] = keyG[(long)b*NN + e];
  int nch = (cnt + CHS - 1)/CHS;
  for (int c=0; c<nch; ++c){
    int kend = (c+1)*CHS; if (kend > cnt) kend = cnt; kend -= 1;
    offB[c][f] = PP[((long)b*NN+kend)*FF+f];
    offD[c][f] = PM[((long)b*NN+kend)*FF+f];
  }
  float rb=0.f, rd=0.f;
  for (int c=0; c<nch; ++c){
    float tb=offB[c][f], td=offD[c][f];
    offB[c][f]=rb; offD[c][f]=rd;
    rb+=tb; rd+=td;
  }
  float TB = rb;
  __syncthreads();
  if (f < TI){
    int r = r0 + f;
    float si=0.f; int k=0;
    if (r < cnt){
      si = SI[r];
      float th = -si;
      int lo=0, hi=cnt;
      while (lo<hi){ int mid=(lo+hi)>>1; if (keys[mid]<=th) lo=mid+1; else hi=mid; }
      k = lo;
    }
    kk[f]=k; sis[f]=si;
  }
  __syncthreads();
  float TBs = SBG[(long)b*NN + (cnt-1)];
  int rmax = cnt - r0; if (rmax > TI) rmax = TI;
  for (int r=0; r<rmax; ++r){
    int k = kk[r]; float si = sis[r];
    float PB=0.f, PD=0.f, SBv=0.f, SDv=0.f;
    if (k > 0){
      int c = (k-1)/CHS;
      PB = PP[((long)b*NN+(k-1))*FF+f] + offB[c][f];
      PD = PM[((long)b*NN+(k-1))*FF+f] + offD[c][f];
      SBv = SBG[(long)b*NN+(k-1)];
      SDv = SDG[(long)b*NN+(k-1)];
    }
    float ai=__expf(si), ci=__expf(SLOPE*si);
    float num = ai*(TB -PB ) + ci*PD;
    float den = ai*(TBs-SBv) + ci*SDv;
    float o2 = num/den;
    xo[(long)(r0+r)*FF + f] = (o2>0.f)? o2 : (__expf(o2)-1.f);
  }
}

// ---- FUSED param head + kld partial + decoder projection (mean in LDS) ----
__global__ __launch_bounds__(256) void k_pardec(const float* __restrict__ XC,
    const float* __restrict__ pW, const float* __restrict__ pB,
    const float* __restrict__ decW, const float* __restrict__ dAd,
    float* __restrict__ KPART, float* __restrict__ H3, float* __restrict__ SJd,
    const int* __restrict__ cntArr)
{
  int b = blockIdx.y; int cnt = cntArr[b];
  int bx = blockIdx.x;
  int r0 = bx*8;
  int t = threadIdx.x;
  if (r0>=cnt){
    if (t==0) KPART[b*NPB + bx] = 0.f;
    return;
  }
  const float* X = XC + (long)b*NN*FF;
  __shared__ float xs[8][FF];
  for (int e=t; e<8*FF; e+=256){
    int r=e>>7, k=e&127; int rr=r0+r;
    xs[r][k] = (rr<cnt) ? X[(long)rr*FF+k] : 0.f;
  }
  __syncthreads();
  float acc[8]={0.f,0.f,0.f,0.f,0.f,0.f,0.f,0.f};
  for (int k=0;k<FF;++k){
    float w = pW[k*2*FF + t];
    #pragma unroll
    for (int r=0;r<8;++r) acc[r]+=xs[r][k]*w;
  }
  float bb = pB[t];
  float kacc=0.f;
  #pragma unroll
  for (int r=0;r<8;++r){
    int rr=r0+r;
    if (rr>=cnt) continue;
    float v = acc[r]+bb;
    if (t<FF) kacc += v*v;
    else kacc += __expf(v)-v-1.f;
  }
  #pragma unroll
  for (int o=32;o;o>>=1) kacc += __shfl_down(kacc,o);
  __shared__ float rw[4];
  if ((t&63)==0) rw[t>>6]=kacc;
  __syncthreads();
  if (t==0) KPART[b*NPB + bx] = rw[0]+rw[1]+rw[2]+rw[3];
  __shared__ float ms[8][FF];
  if (t < FF){
    #pragma unroll
    for (int r=0;r<8;++r){
      int rr=r0+r;
      ms[r][t] = (rr<cnt) ? acc[r]+bb : 0.f;
    }
  }
  __syncthreads();
  int h = t>>7, f = t&127;
  float a2[4]={0.f,0.f,0.f,0.f};
  for (int k=0;k<FF;++k){
    float w = decW[k*FF + f];
    #pragma unroll
    for (int u=0;u<4;++u) a2[u] += ms[h*4+u][k]*w;
  }
  float ad = dAd[f];
  __shared__ float redD[8][2];
  #pragma unroll
  for (int u=0;u<4;++u){
    int rq = h*4+u; int rr = r0+rq;
    if (rr<cnt) H3[((long)b*NN+rr)*FF+f] = a2[u];
    float pd = a2[u]*ad;
    #pragma unroll
    for (int o=32;o;o>>=1) pd += __shfl_down(pd,o);
    if ((t&63)==0) redD[rq][(t>>6)&1]=pd;
  }
  __syncthreads();
  if (t<8){
    int rr=r0+t;
    if (rr<cnt) SJd[(long)b*NN+rr]=redD[t][0]+redD[t][1];
  }
}

// ---- decoder partial reduction: sum_j w_j*h3_j over 64-row chunk ----
__global__ __launch_bounds__(128) void k_dec(const float* __restrict__ H3,
    const float* __restrict__ SJ3, const float* __restrict__ sN,
    const int* __restrict__ cntArr, float* __restrict__ DECP)
{
  int b=blockIdx.y, ch=blockIdx.x;
  int cnt=cntArr[b];
  int f=threadIdx.x;
  int r0=ch*CHS; int r1 = (r0+CHS < cnt) ? r0+CHS : cnt;
  float siN = sN[0];
  const float* H = H3 + (long)b*NN*FF;
  const float* SJ = SJ3 + (long)b*NN;
  float accV=0.f, accW=0.f;
  for (int r=r0;r<r1;++r){
    float sj=SJ[r]; float x=siN+sj;
    float e=(x>=0.f)? x : SLOPE*x;
    float w=__expf(e);
    accV += w*H[(long)r*FF+f];
    accW += w;
  }
  float* P = DECP + (long)(b*NDC+ch)*(FF+1);
  P[f]=accV;
  if (f==0) P[FF]=accW;
}

// ---- head: blocks 0..15 = combine partials + MLP; block 16 = kld ----
__global__ __launch_bounds__(128) void k_head(const float* __restrict__ DECP,
    const float* __restrict__ hN, const float* __restrict__ sN,
    const float* __restrict__ KPART, const int* __restrict__ cntArr,
    const float* __restrict__ W1, const float* __restrict__ b1,
    const float* __restrict__ W2, const float* __restrict__ b2,
    float* __restrict__ out)
{
  int b = blockIdx.x;
  int f = threadIdx.x;
  __shared__ float rw[2];
  if (b < BB){
    float siN=sN[0], sjN=sN[1];
    float xN=siN+sjN; float eN=(xN>=0.f)?xN:SLOPE*xN; float wN=__expf(eN);
    float num=0.f, den=0.f;
    for (int c=0;c<NDC;++c){
      const float* P = DECP + (long)(b*NDC+c)*(FF+1);
      num += P[f]; den += P[FF];
    }
    num += wN*hN[f]; den += wN;
    float v = num/den;
    __shared__ float feats[FF];
    feats[f] = (v>0.f)? v : 0.f;
    __syncthreads();
    float acc=0.f;
    for (int k=0;k<FF;++k) acc += feats[k]*W1[k*FF+f];
    acc += b1[f];
    acc = (acc>0.f)? acc : 0.f;
    float p = acc*W2[f];
    #pragma unroll
    for (int o=32;o;o>>=1) p += __shfl_down(p,o);
    if ((f&63)==0) rw[f>>6]=p;
    __syncthreads();
    if (f==0) out[b] = rw[0]+rw[1]+b2[0];
  } else {
    float s=0.f;
    for (int bb=0;bb<BB;++bb){
      float part=0.f;
      for (int c=f;c<NPB;c+=128) part += KPART[bb*NPB + c];
      #pragma unroll
      for (int o=32;o;o>>=1) part += __shfl_down(part,o);
      if ((f&63)==0) rw[f>>6]=part;
      __syncthreads();
      float tot = rw[0]+rw[1];
      int c=cntArr[bb]; float cf = (c>0)? (float)c : 1.f;
      s += 0.5f*tot/cf;
      __syncthreads();
    }
    if (f==0) out[16]=s;
  }
}

extern "C" void kernel_launch(void* const* d_in, const int* in_sizes, int n_in,
                              void* d_out, int out_size, void* d_ws, size_t ws_size,
                              hipStream_t stream)
{
  const int*   data  = (const int*)d_in[0];
  const float* embed = (const float*)d_in[1];
  const float* encW  = (const float*)d_in[2];
  const float* encAs = (const float*)d_in[3];
  const float* encAd = (const float*)d_in[4];
  const float* pW    = (const float*)d_in[5];
  const float* pB    = (const float*)d_in[6];
  const float* decW  = (const float*)d_in[7];
  const float* decAs = (const float*)d_in[8];
  const float* decAd = (const float*)d_in[9];
  const float* oW1   = (const float*)d_in[10];
  const float* oB1   = (const float*)d_in[11];
  const float* oW2   = (const float*)d_in[12];
  const float* oB2   = (const float*)d_in[13];
  float* out = (float*)d_out;

  float* w = (float*)d_ws;
  long o = 0;
  float* H1   = w+o; o += (long)NN*FF;
  float* H2   = w+o; o += (long)BB*NN*FF;   // layer-2 proj; reused as H3
  float* XC   = w+o; o += (long)BB*NN*FF;   // layer-2 attention output
  float* PP   = w+o; o += (long)BB*NN*FF;
  float* PM   = w+o; o += (long)BB*NN*FF;
  float* SI1  = w+o; o += NN;
  float* SJ1  = w+o; o += NN;
  float* SI2  = w+o; o += (long)BB*NN;
  float* SJ2  = w+o; o += (long)BB*NN;     // enc layer-2 sj; reused for dec sj
  float* KPART= w+o; o += (long)BB*NPB;
  float* hN   = w+o; o += FF;
  float* sN   = w+o; o += 2;
  float* DECP = w+o; o += (long)BB*NDC*(FF+1);
  float* keyG = w+o; o += (long)BB*NN;
  float* SBG  = w+o; o += (long)BB*NN;
  float* SDG  = w+o; o += (long)BB*NN;
  int* act = (int*)(w+o); o += (long)BB*NN;
  int* pjG = (int*)(w+o); o += (long)BB*NN;
  int* cnt = (int*)(w+o); o += BB;
  (void)in_sizes; (void)n_in; (void)out_size; (void)ws_size;

  // layer 1 projection (sample-shared)
  k_rowmm<<<NN/8,128,0,stream>>>(embed, encW, encAs, encAd, H1, SI1, SJ1);
  // compaction + sort + scalar scans (block 16: h_N/s_N)
  k_sortpre<<<BB+1,1024,0,stream>>>(data, embed, decW, decAs, decAd,
      SJ1, 0L, act, cnt, hN, sN, keyG, pjG, SBG, SDG);
  k_chunk<<<dim3(NCH,BB),128,0,stream>>>(keyG, pjG, cnt, H1, 0L, PP, PM);
  // layer-1 attention + layer-2 projection fused
  k_aggout_mm<<<dim3(NN/TI,BB),128,0,stream>>>(keyG, SBG, SDG, PP, PM,
      SI1, act, cnt, encW + FF*FF, encAs + FF, encAd + FF, H2, SI2, SJ2);
  // layer 2 attention
  k_sortpre<<<BB,1024,0,stream>>>(nullptr, embed, decW, decAs, decAd,
      SJ2, (long)NN, act, cnt, hN, sN, keyG, pjG, SBG, SDG);
  k_chunk<<<dim3(NCH,BB),128,0,stream>>>(keyG, pjG, cnt, H2, (long)NN*FF, PP, PM);
  k_aggout<<<dim3(NN/TI,BB),128,0,stream>>>(keyG, SBG, SDG, PP, PM,
      SI2, cnt, XC);
  // param head + kld + decoder projection fused (H3 into H2 buffer, dec sj into SJ2)
  k_pardec<<<dim3(NPB,BB),256,0,stream>>>(XC, pW, pB, decW, decAd,
      KPART, H2 /*H3*/, SJ2 /*dec sj*/, cnt);
  // decoder partial reduction (parallel), then combine + MLP head + kld sum
  k_dec<<<dim3(NDC,BB),128,0,stream>>>(H2 /*H3*/, SJ2, sN, cnt, DECP);
  k_head<<<BB+1,128,0,stream>>>(DECP, hN, sN, KPART, cnt, oW1, oB1, oW2, oB2, out);
}